// Round 7
// baseline (12626.610 us; speedup 1.0000x reference)
//
#include <hip/hip_runtime.h>

#define NUSERS 100000
#define NITEMS 50000
#define NNODES 150000
#define NEDGES 4800000

#define RPB    256                 // rows per block (LDS acc = 256*64*4 = 64 KB)
#define NBLK   586                 // ceil(150000/256)
#define PSHIFT 14                  // 16384-row column panels (2 MB of half-lines)
#define NPAN   10
#define NKEY   (NBLK*NPAN*4)       // 23440 (block, panel, wave) buckets
#define CHUNK  16

typedef unsigned int   uint32;
typedef unsigned short u16;
typedef unsigned long long u64;

// pack two fp32 -> two bf16 (round-to-nearest-even) in one uint
__device__ inline uint32 pack_bf16(float a, float b) {
    uint32 ua = __float_as_uint(a);
    ua += ((ua >> 16) & 1u) + 0x7FFFu;
    uint32 ub = __float_as_uint(b);
    ub += ((ub >> 16) & 1u) + 0x7FFFu;
    return (ua >> 16) | (ub & 0xFFFF0000u);
}

// -------- block boundaries: bb[i] = first edge with row >= i*RPB --------
__global__ void bbound_kernel(const int* __restrict__ rows, int* __restrict__ bb) {
    int i = blockIdx.x * blockDim.x + threadIdx.x;
    if (i > NBLK) return;
    int target = i * RPB;
    int lo = 0, hi = NEDGES;
    while (lo < hi) {
        int mid = (lo + hi) >> 1;
        if (rows[mid] < target) lo = mid + 1; else hi = mid;
    }
    bb[i] = lo;
}

// -------- per-(block, panel, wave) counts --------
__global__ __launch_bounds__(256)
void count_kernel(const int* __restrict__ cols, const int* __restrict__ bb,
                  int* __restrict__ bcnt) {
    int b = blockIdx.x;
    int wv = __builtin_amdgcn_readfirstlane(threadIdx.x >> 6);
    int lane = threadIdx.x & 63;
    int e0 = __builtin_amdgcn_readfirstlane(bb[b]);
    int e1 = __builtin_amdgcn_readfirstlane(bb[b + 1]);
    int len = e1 - e0;
    int wlo = e0 + (len * wv) / 4;
    int whi = e0 + (len * (wv + 1)) / 4;
    int cnt = 0;   // lane p accumulates panel-p count
    for (int base = wlo; base < whi; base += 64) {
        int e = base + lane; int p = -1;
        if (e < whi) p = cols[e] >> PSHIFT;
        #pragma unroll
        for (int pp = 0; pp < NPAN; ++pp) {
            u64 m = __ballot(p == pp);
            if (lane == pp) cnt += (int)__popcll(m);
        }
    }
    if (lane < NPAN) bcnt[b * 40 + lane * 4 + wv] = cnt;
}

// -------- exclusive scan of bcnt[0..NKEY) -> bptr --------
__global__ __launch_bounds__(256)
void scan_kernel(const int* __restrict__ bcnt, int* __restrict__ bptr) {
    __shared__ int sums[256];
    int tid = threadIdx.x;
    const int PT = (NKEY + 255) / 256;   // 92
    int base = tid * PT;
    int s = 0;
    for (int j = 0; j < PT; ++j) { int i = base + j; if (i < NKEY) s += bcnt[i]; }
    sums[tid] = s; __syncthreads();
    for (int off = 1; off < 256; off <<= 1) {
        int x = (tid >= off) ? sums[tid - off] : 0;
        __syncthreads(); sums[tid] += x; __syncthreads();
    }
    int run = sums[tid] - s;
    for (int j = 0; j < PT; ++j) {
        int i = base + j;
        if (i < NKEY) { bptr[i] = run; run += bcnt[i]; }
    }
    if (tid == 255) bptr[NKEY] = NEDGES;
}

// -------- deterministic scatter into bucketed order --------
__global__ __launch_bounds__(256)
void scatter_kernel(const int* __restrict__ rows, const int* __restrict__ cols,
                    const float* __restrict__ vals, const int* __restrict__ bb,
                    const int* __restrict__ bptr,
                    int* __restrict__ cols2, float* __restrict__ vals2) {
    int b = blockIdx.x;
    int wv = __builtin_amdgcn_readfirstlane(threadIdx.x >> 6);
    int lane = threadIdx.x & 63;
    int e0 = __builtin_amdgcn_readfirstlane(bb[b]);
    int e1 = __builtin_amdgcn_readfirstlane(bb[b + 1]);
    int len = e1 - e0;
    int wlo = e0 + (len * wv) / 4;
    int whi = e0 + (len * (wv + 1)) / 4;
    int r0 = b * RPB;
    int curv = 0;
    if (lane < NPAN) curv = bptr[b * 40 + lane * 4 + wv];
    for (int base = wlo; base < whi; base += 64) {
        int e = base + lane;
        int p = -1, c = 0, rr = 0; float v = 0.f;
        if (e < whi) { c = cols[e]; v = vals[e]; rr = rows[e]; p = c >> PSHIFT; }
        u64 mym = 0; int add = 0;
        #pragma unroll
        for (int pp = 0; pp < NPAN; ++pp) {
            u64 m = __ballot(p == pp);
            if (p == pp) mym = m;
            if (lane == pp) add = (int)__popcll(m);
        }
        int basec = __shfl(curv, (p < 0) ? 0 : p);
        if (e < whi) {
            int rank = (int)__popcll(mym & ((1ull << lane) - 1ull));
            int pos = basec + rank;
            cols2[pos] = ((rr - r0) << 18) | c;   // lrow(8b) | col(18b)
            vals2[pos] = v;
        }
        curv += add;
    }
}

// -------- init: hA(bf16) = concat(user,item) --------
__global__ void init_kernel(const float4* __restrict__ ue,
                            const float4* __restrict__ ie,
                            uint2* __restrict__ h,
                            int n_user4, int n_total4) {
    int i = blockIdx.x * blockDim.x + threadIdx.x;
    if (i >= n_total4) return;
    float4 v = (i < n_user4) ? ue[i] : ie[i - n_user4];
    h[i] = make_uint2(pack_bf16(v.x, v.y), pack_bf16(v.z, v.w));
}

// -------- panel-swept SpMM on one 64-dim half, LDS fp32 accumulators --------
template<int LAST>
__global__ __launch_bounds__(256)
void spmm_half(const u16* __restrict__ hsrc16,     // bf16 dims, row stride 128
               const uint32* __restrict__ hsrc32,  // same buffer, u32 view
               uint32* __restrict__ hdst,
               const uint32* __restrict__ h0,
               const uint32* __restrict__ h1,
               float* __restrict__ out,
               const int* __restrict__ cols2,
               const float* __restrict__ vals2,
               const int* __restrict__ bptr,
               int z) {
    __shared__ float acc[RPB * 64];                // 64 KB
    int b = blockIdx.x;
    int tid = threadIdx.x;
    int wv = __builtin_amdgcn_readfirstlane(tid >> 6);
    int lane = tid & 63;
    int r0 = b * RPB;
    int nr = min(RPB, NNODES - r0);

    for (int i = tid; i < RPB * 64; i += 256) acc[i] = 0.f;
    __syncthreads();

    const u16* hs = hsrc16 + z * 64;               // this half's dims

    for (int p = 0; p < NPAN; ++p) {
        int s0 = __builtin_amdgcn_readfirstlane(bptr[b * 40 + p * 4 + wv]);
        int s1 = __builtin_amdgcn_readfirstlane(bptr[b * 40 + p * 4 + wv + 1]);
        for (int c0 = s0; c0 < s1; c0 += CHUNK) {
            int pk[CHUNK]; float sv[CHUNK];
            #pragma unroll
            for (int j = 0; j < CHUNK; ++j) {      // wave-uniform -> s_load
                int e = c0 + j;
                int idx = (e < s1) ? e : (s1 - 1);
                pk[j] = cols2[idx];
                sv[j] = (e < s1) ? vals2[idx] : 0.f;
            }
            uint32 g[CHUNK];
            #pragma unroll
            for (int j = 0; j < CHUNK; ++j) {
                int col = pk[j] & 0x3FFFF;
                g[j] = hs[(uint32)col * 128u + (uint32)lane];
            }
            #pragma unroll
            for (int j = 0; j < CHUNK; ++j) {
                float f = __uint_as_float(g[j] << 16) * sv[j];
                atomicAdd(&acc[((pk[j] >> 18) << 6) + lane], f);  // ds_add_f32
            }
        }
    }
    __syncthreads();

    for (int idx = tid; idx < nr * 32; idx += 256) {
        int r = idx >> 5, j = idx & 31;
        float x = acc[r * 64 + 2 * j];
        float y = acc[r * 64 + 2 * j + 1];
        uint32 off = (uint32)(r0 + r) * 64u + (uint32)z * 32u + (uint32)j;
        if (!LAST) {
            hdst[off] = pack_bf16(x, y);
        } else {
            uint32 a0 = h0[off], a1 = h1[off], a2 = hsrc32[off];
            float ox = 0.25f * (__uint_as_float(a0 << 16) + __uint_as_float(a1 << 16)
                              + __uint_as_float(a2 << 16) + x);
            float oy = 0.25f * (__uint_as_float(a0 & 0xFFFF0000u)
                              + __uint_as_float(a1 & 0xFFFF0000u)
                              + __uint_as_float(a2 & 0xFFFF0000u) + y);
            *reinterpret_cast<float2*>(out + (size_t)(r0 + r) * 128 + z * 64 + 2 * j)
                = make_float2(ox, oy);
        }
    }
}

extern "C" void kernel_launch(void* const* d_in, const int* in_sizes, int n_in,
                              void* d_out, int out_size, void* d_ws, size_t ws_size,
                              hipStream_t stream) {
    const float* ue   = (const float*)d_in[0];
    const float* ie   = (const float*)d_in[1];
    const int*   rows = (const int*)  d_in[2];
    const int*   cols = (const int*)  d_in[3];
    const float* vals = (const float*)d_in[4];
    float* out = (float*)d_out;

    char* ws = (char*)d_ws;
    size_t o = 0;
    auto carve = [&](size_t bytes) { char* p = ws + o; o = (o + bytes + 255) & ~(size_t)255; return p; };
    int*    bb    = (int*)   carve((size_t)(NBLK + 1) * 4);
    int*    bcnt  = (int*)   carve((size_t)NKEY * 4);
    int*    bptr  = (int*)   carve((size_t)(NKEY + 1) * 4);
    int*    cols2 = (int*)   carve((size_t)NEDGES * 4);
    float*  vals2 = (float*) carve((size_t)NEDGES * 4);
    uint32* hA    = (uint32*)carve((size_t)NNODES * 64 * 4);
    uint32* hB    = (uint32*)carve((size_t)NNODES * 64 * 4);
    uint32* hC    = (uint32*)carve((size_t)NNODES * 64 * 4);

    // preprocessing
    bbound_kernel<<<(NBLK + 1 + 255) / 256, 256, 0, stream>>>(rows, bb);
    count_kernel<<<NBLK, 256, 0, stream>>>(cols, bb, bcnt);
    scan_kernel<<<1, 256, 0, stream>>>(bcnt, bptr);
    scatter_kernel<<<NBLK, 256, 0, stream>>>(rows, cols, vals, bb, bptr, cols2, vals2);
    init_kernel<<<(NNODES * 32 + 255) / 256, 256, 0, stream>>>(
        (const float4*)ue, (const float4*)ie, (uint2*)hA, NUSERS * 32, NNODES * 32);

    // layer 1: hA -> hB
    for (int z = 0; z < 2; ++z)
        spmm_half<0><<<NBLK, 256, 0, stream>>>(
            (const u16*)hA, hA, hB, nullptr, nullptr, out, cols2, vals2, bptr, z);
    // layer 2: hB -> hC
    for (int z = 0; z < 2; ++z)
        spmm_half<0><<<NBLK, 256, 0, stream>>>(
            (const u16*)hB, hB, hC, nullptr, nullptr, out, cols2, vals2, bptr, z);
    // layer 3 fused with final combine: src hC, out = 0.25*(hA+hB+hC+h3)
    for (int z = 0; z < 2; ++z)
        spmm_half<1><<<NBLK, 256, 0, stream>>>(
            (const u16*)hC, hC, nullptr, hA, hB, out, cols2, vals2, bptr, z);
}

// Round 8
// 1285.224 us; speedup vs baseline: 9.8244x; 9.8244x over previous
//
#include <hip/hip_runtime.h>

#define NUSERS 100000
#define NITEMS 50000
#define NNODES 150000
#define NEDGES 4800000

#define RPB    147                 // rows per block; LDS acc = 148*128*4 = 75776 B -> 2 blocks/CU
#define NBLK   1021                // ceil(150000/147)
#define NSLICE (NBLK*4)            // 4084 wave-slices (37/37/37/36 rows)
#define PSHIFT 13                  // 8192-row column panels (2 MB of bf16 rows)
#define NPAN   19
#define NKEY   (NSLICE*NPAN)       // 77596
#define DUMP   147                 // dump row for merged/padded slots
#define CHUNK  8

typedef unsigned int uint32;
typedef unsigned long long u64;

__device__ inline uint32 pack_bf16(float a, float b) {
    uint32 ua = __float_as_uint(a);
    ua += ((ua >> 16) & 1u) + 0x7FFFu;
    uint32 ub = __float_as_uint(b);
    ub += ((ub >> 16) & 1u) + 0x7FFFu;
    return (ua >> 16) | (ub & 0xFFFF0000u);
}

// slice start row: slice i covers rows [rs(i), rs(i+1))
__device__ inline int slice_row(int i) {
    int rs = (i >> 2) * RPB + (i & 3) * 37;
    return rs > NNODES ? NNODES : rs;
}

// -------- slice edge boundaries via binary search on sorted rows --------
__global__ void bbound_kernel(const int* __restrict__ rows, int* __restrict__ bb2) {
    int i = blockIdx.x * blockDim.x + threadIdx.x;
    if (i > NSLICE) return;
    int target = slice_row(i);
    int lo = 0, hi = NEDGES;
    while (lo < hi) {
        int mid = (lo + hi) >> 1;
        if (rows[mid] < target) lo = mid + 1; else hi = mid;
    }
    bb2[i] = lo;
}

// -------- per-(slice, panel) counts, written into bptr (scanned in place) --------
__global__ __launch_bounds__(256)
void count_kernel(const int* __restrict__ cols, const int* __restrict__ bb2,
                  int* __restrict__ bptr) {
    int w = blockIdx.x * 4 + (threadIdx.x >> 6);
    int lane = threadIdx.x & 63;
    int e0 = __builtin_amdgcn_readfirstlane(bb2[w]);
    int e1 = __builtin_amdgcn_readfirstlane(bb2[w + 1]);
    int cnt = 0;
    for (int base = e0; base < e1; base += 64) {
        int e = base + lane; int p = -1;
        if (e < e1) p = cols[e] >> PSHIFT;
        #pragma unroll
        for (int pp = 0; pp < NPAN; ++pp) {
            u64 m = __ballot(p == pp);
            if (lane == pp) cnt += (int)__popcll(m);
        }
    }
    if (lane < NPAN) bptr[w * NPAN + lane] = cnt;
}

// -------- single-block in-place exclusive scan of bptr[0..NKEY) --------
__global__ __launch_bounds__(256)
void scan_kernel(int* __restrict__ bptr) {
    __shared__ int sums[256];
    const int PT = (NKEY + 255) / 256;      // 304
    int tid = threadIdx.x;
    int base = tid * PT;
    int s = 0;
    for (int j = 0; j < PT; ++j) { int i = base + j; if (i < NKEY) s += bptr[i]; }
    sums[tid] = s; __syncthreads();
    for (int off = 1; off < 256; off <<= 1) {
        int x = (tid >= off) ? sums[tid - off] : 0;
        __syncthreads(); sums[tid] += x; __syncthreads();
    }
    int run = sums[tid] - s;
    for (int j = 0; j < PT; ++j) {
        int i = base + j;
        if (i < NKEY) { int v = bptr[i]; bptr[i] = run; run += v; }
    }
    if (tid == 255) bptr[NKEY] = NEDGES;
}

// -------- deterministic scatter into (slice, panel)-bucketed order --------
__global__ __launch_bounds__(256)
void scatter_kernel(const int* __restrict__ rows, const int* __restrict__ cols,
                    const float* __restrict__ vals, const int* __restrict__ bb2,
                    const int* __restrict__ bptr,
                    int* __restrict__ cols2, float* __restrict__ vals2) {
    int w = blockIdx.x * 4 + (threadIdx.x >> 6);
    int lane = threadIdx.x & 63;
    int e0 = __builtin_amdgcn_readfirstlane(bb2[w]);
    int e1 = __builtin_amdgcn_readfirstlane(bb2[w + 1]);
    int b = w >> 2;
    int cur = 0;
    if (lane < NPAN) cur = bptr[w * NPAN + lane];
    for (int base = e0; base < e1; base += 64) {
        int e = base + lane;
        int p = -1, c = 0, rr = 0; float v = 0.f;
        if (e < e1) { c = cols[e]; v = vals[e]; rr = rows[e]; p = c >> PSHIFT; }
        u64 mym = 0; int add = 0;
        #pragma unroll
        for (int pp = 0; pp < NPAN; ++pp) {
            u64 m = __ballot(p == pp);
            if (p == pp) mym = m;
            if (lane == pp) add = (int)__popcll(m);
        }
        int basec = __shfl(cur, (p < 0) ? 0 : p);
        if (e < e1) {
            int rank = (int)__popcll(mym & ((1ull << lane) - 1ull));
            int pos = basec + rank;
            cols2[pos] = ((rr - b * RPB) << 18) | c;   // lrow(8b) | col(18b)
            vals2[pos] = v;
        }
        cur += add;
    }
}

// -------- init: hA(bf16) = concat(user,item) --------
__global__ void init_kernel(const float4* __restrict__ ue,
                            const float4* __restrict__ ie,
                            uint2* __restrict__ h,
                            int n_user4, int n_total4) {
    int i = blockIdx.x * blockDim.x + threadIdx.x;
    if (i >= n_total4) return;
    float4 v = (i < n_user4) ? ue[i] : ie[i - n_user4];
    h[i] = make_uint2(pack_bf16(v.x, v.y), pack_bf16(v.z, v.w));
}

// -------- panel-swept SpMM, full dim, LDS fp32 acc, non-atomic RMW --------
template<int LAST>
__global__ __launch_bounds__(256)
void spmm_panel(const uint32* __restrict__ hsrc,   // bf16x2 words, row stride 64
                uint32* __restrict__ hdst,
                const uint32* __restrict__ h0,
                const uint32* __restrict__ h1,
                float* __restrict__ out,
                const int* __restrict__ cols2,
                const float* __restrict__ vals2,
                const int* __restrict__ bptr) {
    __shared__ float acc[148 * 128];               // 75776 B
    int b = blockIdx.x, tid = threadIdx.x;
    int wv = tid >> 6, lane = tid & 63;
    int r0 = b * RPB;
    int nr = min(RPB, NNODES - r0);

    for (int i = tid; i < 148 * 128 / 4; i += 256)
        reinterpret_cast<float4*>(acc)[i] = make_float4(0.f, 0.f, 0.f, 0.f);
    __syncthreads();

    int kbase = __builtin_amdgcn_readfirstlane(b * 4 + wv) * NPAN;

    for (int p = 0; p < NPAN; ++p) {
        int s0 = __builtin_amdgcn_readfirstlane(bptr[kbase + p]);
        int s1 = __builtin_amdgcn_readfirstlane(bptr[kbase + p + 1]);
        for (int c0 = s0; c0 < s1; c0 += CHUNK) {
            // metadata (wave-uniform -> scalar regs); tail clamps with val=0
            int pk[CHUNK]; float sv[CHUNK];
            #pragma unroll
            for (int t = 0; t < CHUNK; ++t) {
                int e = c0 + t;
                int idx = (e < s1) ? e : (s1 - 1);
                pk[t] = cols2[idx];
                sv[t] = (e < s1) ? vals2[idx] : 0.f;
            }
            // gathers: one edge per wave-instruction, lane = dim word
            uint32 g[CHUNK];
            #pragma unroll
            for (int t = 0; t < CHUNK; ++t)
                g[t] = hsrc[(uint32)(pk[t] & 0x3FFFF) * 64u + (uint32)lane];
            // products
            float px[CHUNK], py[CHUNK];
            #pragma unroll
            for (int t = 0; t < CHUNK; ++t) {
                uint32 u = g[t];
                px[t] = sv[t] * __uint_as_float(u << 16);
                py[t] = sv[t] * __uint_as_float(u & 0xFFFF0000u);
            }
            // run-merge cascade: bucket is row-sorted -> equal rows adjacent.
            // all but the last edge of a run redirect to DUMP; last gets the sum.
            int ar[CHUNK];
            #pragma unroll
            for (int t = 0; t < CHUNK; ++t) ar[t] = pk[t] >> 18;
            #pragma unroll
            for (int t = 0; t < CHUNK - 1; ++t) {
                bool eq = (ar[t] == (pk[t + 1] >> 18));
                px[t + 1] += eq ? px[t] : 0.f;
                py[t + 1] += eq ? py[t] : 0.f;
                if (eq) ar[t] = DUMP;
            }
            // batched RMW: 8 reads (live addresses distinct), add, 8 writes
            float2 old[CHUNK];
            #pragma unroll
            for (int t = 0; t < CHUNK; ++t)
                old[t] = *reinterpret_cast<float2*>(&acc[ar[t] * 128 + lane * 2]);
            #pragma unroll
            for (int t = 0; t < CHUNK; ++t) { old[t].x += px[t]; old[t].y += py[t]; }
            #pragma unroll
            for (int t = 0; t < CHUNK; ++t)
                *reinterpret_cast<float2*>(&acc[ar[t] * 128 + lane * 2]) = old[t];
        }
    }
    __syncthreads();

    for (int idx = tid; idx < nr * 64; idx += 256) {
        int r = idx >> 6, wd = idx & 63;
        float x = acc[r * 128 + 2 * wd];
        float y = acc[r * 128 + 2 * wd + 1];
        uint32 off = (uint32)(r0 + r) * 64u + (uint32)wd;
        if (!LAST) {
            hdst[off] = pack_bf16(x, y);
        } else {
            uint32 a0 = h0[off], a1 = h1[off], a2 = hsrc[off];
            float ox = 0.25f * (__uint_as_float(a0 << 16) + __uint_as_float(a1 << 16)
                              + __uint_as_float(a2 << 16) + x);
            float oy = 0.25f * (__uint_as_float(a0 & 0xFFFF0000u)
                              + __uint_as_float(a1 & 0xFFFF0000u)
                              + __uint_as_float(a2 & 0xFFFF0000u) + y);
            *reinterpret_cast<float2*>(out + (size_t)(r0 + r) * 128 + 2 * wd)
                = make_float2(ox, oy);
        }
    }
}

extern "C" void kernel_launch(void* const* d_in, const int* in_sizes, int n_in,
                              void* d_out, int out_size, void* d_ws, size_t ws_size,
                              hipStream_t stream) {
    const float* ue   = (const float*)d_in[0];
    const float* ie   = (const float*)d_in[1];
    const int*   rows = (const int*)  d_in[2];
    const int*   cols = (const int*)  d_in[3];
    const float* vals = (const float*)d_in[4];
    float* out = (float*)d_out;

    char* ws = (char*)d_ws;
    size_t o = 0;
    auto carve = [&](size_t bytes) { char* p = ws + o; o = (o + bytes + 255) & ~(size_t)255; return p; };
    int*    bb2   = (int*)   carve((size_t)(NSLICE + 1) * 4);
    int*    bptr  = (int*)   carve((size_t)(NKEY + 1) * 4);
    int*    cols2 = (int*)   carve((size_t)NEDGES * 4);
    float*  vals2 = (float*) carve((size_t)NEDGES * 4);
    uint32* hA    = (uint32*)carve((size_t)NNODES * 64 * 4);
    uint32* hB    = (uint32*)carve((size_t)NNODES * 64 * 4);
    uint32* hC    = (uint32*)carve((size_t)NNODES * 64 * 4);

    // preprocessing
    bbound_kernel<<<(NSLICE + 1 + 255) / 256, 256, 0, stream>>>(rows, bb2);
    count_kernel<<<NBLK, 256, 0, stream>>>(cols, bb2, bptr);
    scan_kernel<<<1, 256, 0, stream>>>(bptr);
    scatter_kernel<<<NBLK, 256, 0, stream>>>(rows, cols, vals, bb2, bptr, cols2, vals2);
    init_kernel<<<(NNODES * 32 + 255) / 256, 256, 0, stream>>>(
        (const float4*)ue, (const float4*)ie, (uint2*)hA, NUSERS * 32, NNODES * 32);

    // three panel-swept SpMM layers; last fused with final combine
    spmm_panel<0><<<NBLK, 256, 0, stream>>>(hA, hB, nullptr, nullptr, out, cols2, vals2, bptr);
    spmm_panel<0><<<NBLK, 256, 0, stream>>>(hB, hC, nullptr, nullptr, out, cols2, vals2, bptr);
    spmm_panel<1><<<NBLK, 256, 0, stream>>>(hC, nullptr, hA, hB, out, cols2, vals2, bptr);
}

// Round 10
// 855.323 us; speedup vs baseline: 14.7624x; 1.5026x over previous
//
#include <hip/hip_runtime.h>

#define NUSERS 100000
#define NITEMS 50000
#define NNODES 150000
#define NEDGES 4800000

#define RPB    64                  // rows per block; LDS acc = 65*128*4 = 33280 B -> 4 blocks/CU
#define NBLK   2344                // ceil(150000/64)
#define NSLICE (NBLK*4)            // 9376 wave-slices of 16 rows
#define PSHIFT 13                  // 8192-row column panels (2 MB of bf16 rows)
#define NPAN   19
#define NKEY   (NSLICE*NPAN)       // 178144
#define DUMP   64                  // dump row for merged/padded slots
#define CH     16                  // chunk (edges per pipeline stage)
#define EMAX   7900000             // >= NEDGES + NSLICE*(19*15+31)

typedef unsigned int   uint32;
typedef unsigned short u16;
typedef unsigned long long u64;

__device__ inline uint32 pack_bf16(float a, float b) {
    uint32 ua = __float_as_uint(a);
    ua += ((ua >> 16) & 1u) + 0x7FFFu;
    uint32 ub = __float_as_uint(b);
    ub += ((ub >> 16) & 1u) + 0x7FFFu;
    return (ua >> 16) | (ub & 0xFFFF0000u);
}

__device__ inline int slice_row(int i) {
    int rs = i * 16;
    return rs > NNODES ? NNODES : rs;
}

// -------- slice edge boundaries via binary search on sorted rows --------
__global__ void bbound_kernel(const int* __restrict__ rows, int* __restrict__ bb2) {
    int i = blockIdx.x * blockDim.x + threadIdx.x;
    if (i > NSLICE) return;
    int target = slice_row(i);
    int lo = 0, hi = NEDGES;
    while (lo < hi) {
        int mid = (lo + hi) >> 1;
        if (rows[mid] < target) lo = mid + 1; else hi = mid;
    }
    bb2[i] = lo;
}

// -------- per-(slice, panel) counts --------
__global__ __launch_bounds__(256)
void count_kernel(const int* __restrict__ cols, const int* __restrict__ bb2,
                  int* __restrict__ cnt) {
    int w = blockIdx.x * 4 + (threadIdx.x >> 6);
    int lane = threadIdx.x & 63;
    int e0 = __builtin_amdgcn_readfirstlane(bb2[w]);
    int e1 = __builtin_amdgcn_readfirstlane(bb2[w + 1]);
    int c = 0;
    for (int base = e0; base < e1; base += 64) {
        int e = base + lane; int p = -1;
        if (e < e1) p = cols[e] >> PSHIFT;
        #pragma unroll
        for (int pp = 0; pp < NPAN; ++pp) {
            u64 m = __ballot(p == pp);
            if (lane == pp) c += (int)__popcll(m);
        }
    }
    if (lane < NPAN) cnt[w * NPAN + lane] = c;
}

// -------- single-block scan: bucket starts padded to 16, slices to 32 --------
__global__ __launch_bounds__(256)
void scan_kernel(const int* __restrict__ cnt, int* __restrict__ kstart,
                 int* __restrict__ pend) {
    __shared__ int sums[256];
    int tid = threadIdx.x;
    const int SPT = (NSLICE + 255) / 256;   // 37
    int lo = tid * SPT, hi = min(NSLICE, lo + SPT);
    int s = 0;
    for (int w = lo; w < hi; ++w) {
        int t = 0;
        for (int p = 0; p < NPAN; ++p) t += (cnt[w * NPAN + p] + 15) & ~15;
        s += (t + 31) & ~31;
    }
    sums[tid] = s; __syncthreads();
    for (int off = 1; off < 256; off <<= 1) {
        int x = (tid >= off) ? sums[tid - off] : 0;
        __syncthreads(); sums[tid] += x; __syncthreads();
    }
    int run = sums[tid] - s;
    for (int w = lo; w < hi; ++w) {
        int cur = run;
        for (int p = 0; p < NPAN; ++p) {
            kstart[w * NPAN + p] = cur;
            cur += (cnt[w * NPAN + p] + 15) & ~15;
        }
        int tot = cur - run;
        pend[w] = run + ((tot + 31) & ~31);
        run = pend[w];
    }
}

// -------- fill meta with pad pattern (row DUMP, col 0, val 0) --------
__global__ void fill_kernel(uint32* __restrict__ keys, uint32* __restrict__ vals32) {
    int i = blockIdx.x * blockDim.x + threadIdx.x;
    int stride = gridDim.x * blockDim.x;
    for (int k = i; k < EMAX; k += stride) keys[k] = (DUMP << 18);
    for (int k = i; k < EMAX / 2; k += stride) vals32[k] = 0u;
}

// -------- deterministic scatter into padded (slice, panel) buckets --------
__global__ __launch_bounds__(256)
void scatter_kernel(const int* __restrict__ rows, const int* __restrict__ cols,
                    const float* __restrict__ vals, const int* __restrict__ bb2,
                    const int* __restrict__ kstart,
                    uint32* __restrict__ keys, u16* __restrict__ vals16) {
    int w = blockIdx.x * 4 + (threadIdx.x >> 6);
    int lane = threadIdx.x & 63;
    int e0 = __builtin_amdgcn_readfirstlane(bb2[w]);
    int e1 = __builtin_amdgcn_readfirstlane(bb2[w + 1]);
    int b = w >> 2;
    int cur = 0;
    if (lane < NPAN) cur = kstart[w * NPAN + lane];
    for (int base = e0; base < e1; base += 64) {
        int e = base + lane;
        int p = -1, c = 0, rr = 0; float v = 0.f;
        if (e < e1) { c = cols[e]; v = vals[e]; rr = rows[e]; p = c >> PSHIFT; }
        u64 mym = 0; int add = 0;
        #pragma unroll
        for (int pp = 0; pp < NPAN; ++pp) {
            u64 m = __ballot(p == pp);
            if (p == pp) mym = m;
            if (lane == pp) add = (int)__popcll(m);
        }
        int basec = __shfl(cur, (p < 0) ? 0 : p);
        if (e < e1) {
            int rank = (int)__popcll(mym & ((1ull << lane) - 1ull));
            int pos = basec + rank;
            keys[pos] = ((uint32)(rr - b * RPB) << 18) | (uint32)c;
            vals16[pos] = (u16)(pack_bf16(v, 0.f) & 0xFFFFu);
        }
        cur += add;
    }
}

// -------- init: hA(bf16) = concat(user,item) --------
__global__ void init_kernel(const float4* __restrict__ ue,
                            const float4* __restrict__ ie,
                            uint2* __restrict__ h,
                            int n_user4, int n_total4) {
    int i = blockIdx.x * blockDim.x + threadIdx.x;
    if (i >= n_total4) return;
    float4 v = (i < n_user4) ? ue[i] : ie[i - n_user4];
    h[i] = make_uint2(pack_bf16(v.x, v.y), pack_bf16(v.z, v.w));
}

// -------- panel-ordered SpMM: LDS fp32 acc, 2-deep pipelined chunks --------
template<int LAST>
__global__ __launch_bounds__(256)
void spmm_pipe(const uint32* __restrict__ hsrc,   // bf16x2 words, row stride 64
               uint32* __restrict__ hdst,
               const uint32* __restrict__ h0,
               const uint32* __restrict__ h1,
               float* __restrict__ out,
               const uint32* __restrict__ keys,
               const uint32* __restrict__ vals32,
               const int* __restrict__ kstart,
               const int* __restrict__ pend) {
    __shared__ float acc[65 * 128];                // 33280 B
    int b = blockIdx.x, tid = threadIdx.x;
    int lane = tid & 63;
    int w = __builtin_amdgcn_readfirstlane(b * 4 + (tid >> 6));
    int r0 = b * RPB;

    for (int i = tid; i < 65 * 128 / 4; i += 256)
        reinterpret_cast<float4*>(acc)[i] = make_float4(0.f, 0.f, 0.f, 0.f);
    __syncthreads();

    int E  = __builtin_amdgcn_readfirstlane(kstart[w * NPAN]);
    int E1 = __builtin_amdgcn_readfirstlane(pend[w]);
    int n = (E1 - E) >> 5;                         // 32-edge steps (padded)

    float2* accl = reinterpret_cast<float2*>(acc) + lane;

    int pk0[CH], pk1[CH]; float sv0[CH], sv1[CH]; uint32 g0[CH], g1[CH];

#define LOADMETA(PK, SV, BASE) do {                                          \
    _Pragma("unroll")                                                        \
    for (int j = 0; j < CH; ++j)                                             \
        PK[j] = __builtin_amdgcn_readfirstlane((int)keys[(BASE) + j]);       \
    _Pragma("unroll")                                                        \
    for (int j = 0; j < CH / 2; ++j) {                                       \
        uint32 vv = (uint32)__builtin_amdgcn_readfirstlane(                  \
                        (int)vals32[((BASE) >> 1) + j]);                     \
        SV[2 * j]     = __uint_as_float(vv << 16);                           \
        SV[2 * j + 1] = __uint_as_float(vv & 0xFFFF0000u);                   \
    } } while (0)

#define GATHER(G, PK) do {                                                   \
    _Pragma("unroll")                                                        \
    for (int j = 0; j < CH; ++j)                                             \
        G[j] = hsrc[((uint32)PK[j] & 0x3FFFFu) * 64u + (uint32)lane];        \
    } while (0)

#define CONSUME(G, PK, SV) do {                                              \
    float px[CH], py[CH]; int ar[CH];                                        \
    _Pragma("unroll")                                                        \
    for (int j = 0; j < CH; ++j) {                                           \
        uint32 u = G[j];                                                     \
        px[j] = SV[j] * __uint_as_float(u << 16);                            \
        py[j] = SV[j] * __uint_as_float(u & 0xFFFF0000u);                    \
        ar[j] = PK[j] >> 18;                                                 \
    }                                                                        \
    _Pragma("unroll")                                                        \
    for (int j = 0; j < CH - 1; ++j) {                                       \
        bool eq = (ar[j] == (PK[j + 1] >> 18));                              \
        px[j + 1] += eq ? px[j] : 0.f;                                       \
        py[j + 1] += eq ? py[j] : 0.f;                                       \
        if (eq) ar[j] = DUMP;                                                \
    }                                                                        \
    _Pragma("unroll")                                                        \
    for (int h8 = 0; h8 < CH; h8 += 8) {                                     \
        float2 o[8];                                                         \
        _Pragma("unroll")                                                    \
        for (int j = 0; j < 8; ++j) o[j] = accl[ar[h8 + j] * 64];            \
        _Pragma("unroll")                                                    \
        for (int j = 0; j < 8; ++j) { o[j].x += px[h8 + j]; o[j].y += py[h8 + j]; } \
        _Pragma("unroll")                                                    \
        for (int j = 0; j < 8; ++j) accl[ar[h8 + j] * 64] = o[j];            \
    } } while (0)

    if (n > 0) {
        LOADMETA(pk0, sv0, E);      GATHER(g0, pk0);
        LOADMETA(pk1, sv1, E + CH); GATHER(g1, pk1);
        for (int i = 1; i < n; ++i) {
            CONSUME(g0, pk0, sv0);
            LOADMETA(pk0, sv0, E + 32); GATHER(g0, pk0);
            CONSUME(g1, pk1, sv1);
            LOADMETA(pk1, sv1, E + 48); GATHER(g1, pk1);
            E += 32;
        }
        CONSUME(g0, pk0, sv0);
        CONSUME(g1, pk1, sv1);
    }
#undef LOADMETA
#undef GATHER
#undef CONSUME
    __syncthreads();

    int nr = min(RPB, NNODES - r0);
    for (int idx = tid; idx < nr * 64; idx += 256) {
        int r = idx >> 6, wd = idx & 63;
        float x = acc[r * 128 + 2 * wd];
        float y = acc[r * 128 + 2 * wd + 1];
        uint32 off = (uint32)(r0 + r) * 64u + (uint32)wd;
        if (!LAST) {
            hdst[off] = pack_bf16(x, y);
        } else {
            uint32 a0 = h0[off], a1 = h1[off], a2 = hsrc[off];
            float ox = 0.25f * (__uint_as_float(a0 << 16) + __uint_as_float(a1 << 16)
                              + __uint_as_float(a2 << 16) + x);
            float oy = 0.25f * (__uint_as_float(a0 & 0xFFFF0000u)
                              + __uint_as_float(a1 & 0xFFFF0000u)
                              + __uint_as_float(a2 & 0xFFFF0000u) + y);
            *reinterpret_cast<float2*>(out + (size_t)(r0 + r) * 128 + 2 * wd)
                = make_float2(ox, oy);
        }
    }
}

extern "C" void kernel_launch(void* const* d_in, const int* in_sizes, int n_in,
                              void* d_out, int out_size, void* d_ws, size_t ws_size,
                              hipStream_t stream) {
    const float* ue   = (const float*)d_in[0];
    const float* ie   = (const float*)d_in[1];
    const int*   rows = (const int*)  d_in[2];
    const int*   cols = (const int*)  d_in[3];
    const float* vals = (const float*)d_in[4];
    float* out = (float*)d_out;

    char* ws = (char*)d_ws;
    size_t o = 0;
    auto carve = [&](size_t bytes) { char* p = ws + o; o = (o + bytes + 255) & ~(size_t)255; return p; };
    int*    bb2    = (int*)   carve((size_t)(NSLICE + 1) * 4);
    int*    cnt    = (int*)   carve((size_t)NKEY * 4);
    int*    kstart = (int*)   carve((size_t)NKEY * 4);
    int*    pend   = (int*)   carve((size_t)NSLICE * 4);
    uint32* keys   = (uint32*)carve((size_t)EMAX * 4);
    u16*    vals16 = (u16*)   carve((size_t)EMAX * 2);
    uint32* hA     = (uint32*)carve((size_t)NNODES * 64 * 4);
    uint32* hB     = (uint32*)carve((size_t)NNODES * 64 * 4);
    uint32* hC     = (uint32*)carve((size_t)NNODES * 64 * 4);

    // preprocessing
    bbound_kernel<<<(NSLICE + 1 + 255) / 256, 256, 0, stream>>>(rows, bb2);
    count_kernel<<<NBLK, 256, 0, stream>>>(cols, bb2, cnt);
    scan_kernel<<<1, 256, 0, stream>>>(cnt, kstart, pend);
    fill_kernel<<<2048, 256, 0, stream>>>(keys, (uint32*)vals16);
    scatter_kernel<<<NBLK, 256, 0, stream>>>(rows, cols, vals, bb2, kstart, keys, vals16);
    init_kernel<<<(NNODES * 32 + 255) / 256, 256, 0, stream>>>(
        (const float4*)ue, (const float4*)ie, (uint2*)hA, NUSERS * 32, NNODES * 32);

    // three panel-ordered SpMM layers; last fused with final combine
    spmm_pipe<0><<<NBLK, 256, 0, stream>>>(hA, hB, nullptr, nullptr, out,
                                           keys, (const uint32*)vals16, kstart, pend);
    spmm_pipe<0><<<NBLK, 256, 0, stream>>>(hB, hC, nullptr, nullptr, out,
                                           keys, (const uint32*)vals16, kstart, pend);
    spmm_pipe<1><<<NBLK, 256, 0, stream>>>(hC, nullptr, hA, hB, out,
                                           keys, (const uint32*)vals16, kstart, pend);
}

// Round 12
// 551.909 us; speedup vs baseline: 22.8781x; 1.5498x over previous
//
#include <hip/hip_runtime.h>

#define NUSERS 100000
#define NITEMS 50000
#define NNODES 150000
#define DIM    128
#define NEDGES 4800000

typedef unsigned int uint32;
typedef unsigned long long u64;

// pack two fp32 -> two bf16 (round-to-nearest-even) in one uint
__device__ inline uint32 pack_bf16(float a, float b) {
    uint32 ua = __float_as_uint(a);
    ua += ((ua >> 16) & 1u) + 0x7FFFu;
    uint32 ub = __float_as_uint(b);
    ub += ((ub >> 16) & 1u) + 0x7FFFu;
    return (ua >> 16) | (ub & 0xFFFF0000u);
}

// -------- row_ptr from sorted COO rows: lower_bound per node --------
__global__ void build_rowptr(const int* __restrict__ rows,
                             int* __restrict__ rowptr,
                             int n_nodes, int n_edges) {
    int r = blockIdx.x * blockDim.x + threadIdx.x;
    if (r > n_nodes) return;
    int lo = 0, hi = n_edges;
    while (lo < hi) {
        int mid = (lo + hi) >> 1;
        if (rows[mid] < r) lo = mid + 1; else hi = mid;
    }
    rowptr[r] = lo;
}

// -------- init: h0(bf16) = concat(user,item) --------
__global__ void init_kernel(const float4* __restrict__ ue,
                            const float4* __restrict__ ie,
                            uint2* __restrict__ h,      // 4 bf16 per uint2
                            int n_user4, int n_total4) {
    int i = blockIdx.x * blockDim.x + threadIdx.x;
    if (i >= n_total4) return;
    float4 v = (i < n_user4) ? ue[i] : ie[i - n_user4];
    h[i] = make_uint2(pack_bf16(v.x, v.y), pack_bf16(v.z, v.w));
}

// Straight-line S-slot row segment: scalar (wave-uniform) cols/vals loads,
// all S gathers issued before consumption. Tail slots clamp to hi-1 with
// val=0 (harmless re-gather of a hot line).
template<int S>
__device__ __forceinline__ void row_fixed(const uint32* __restrict__ h,
                                          const int* __restrict__ cols,
                                          const float* __restrict__ vals,
                                          int lo, int hi, int lane,
                                          float& sx, float& sy) {
    int   sc[S];
    float sv[S];
    uint32 buf[S];
    #pragma unroll
    for (int j = 0; j < S; ++j) {
        int e = lo + j;                       // wave-uniform
        int idx = e < hi ? e : hi - 1;        // uniform select -> s_cselect
        sc[j] = cols[idx];                    // s_load (merged)
        sv[j] = e < hi ? vals[idx] : 0.f;     // s_load + s_cselect
    }
    #pragma unroll
    for (int j = 0; j < S; ++j)
        buf[j] = h[(uint32)sc[j] * 64u + (uint32)lane];
    #pragma unroll
    for (int j = 0; j < S; ++j) {
        uint32 u = buf[j];
        sx += sv[j] * __uint_as_float(u << 16);
        sy += sv[j] * __uint_as_float(u & 0xFFFF0000u);
    }
}

__device__ __forceinline__ void row_dispatch(const uint32* __restrict__ h,
                                             const int* __restrict__ cols,
                                             const float* __restrict__ vals,
                                             int lo, int hi, int lane,
                                             float& sx, float& sy) {
    int len = hi - lo;
    if (len <= 0) return;
    if      (len <= 16) row_fixed<16>(h, cols, vals, lo, hi, lane, sx, sy);
    else if (len <= 32) row_fixed<32>(h, cols, vals, lo, hi, lane, sx, sy);
    else if (len <= 48) row_fixed<48>(h, cols, vals, lo, hi, lane, sx, sy);
    else if (len <= 64) row_fixed<64>(h, cols, vals, lo, hi, lane, sx, sy);
    else {
        for (int b = lo; b < hi; b += 64)
            row_fixed<64>(h, cols, vals, b, hi, lane, sx, sy);
    }
}

// -------- mid layers: h_new[r] = sum vals*h[cols], bf16 store only --------
__global__ __launch_bounds__(256)
void spmm_mid(const uint32* __restrict__ h,
              uint32* __restrict__ hn,
              const int* __restrict__ cols,
              const float* __restrict__ vals,
              const int* __restrict__ rowptr,
              int n_nodes) {
    int wave = (int)((blockIdx.x * blockDim.x + threadIdx.x) >> 6);
    int lane = threadIdx.x & 63;
    if (wave >= n_nodes) return;

    int lo = __builtin_amdgcn_readfirstlane(rowptr[wave]);
    int hi = __builtin_amdgcn_readfirstlane(rowptr[wave + 1]);

    float sx = 0.f, sy = 0.f;
    row_dispatch(h, cols, vals, lo, hi, lane, sx, sy);

    hn[(uint32)wave * 64u + (uint32)lane] = pack_bf16(sx, sy);
}

// -------- last layer fused with final combine --------
// out[r] = (h0[r] + h1[r] + h2[r] + h3[r]) * 0.25, h3 computed in regs
__global__ __launch_bounds__(256)
void spmm_last(const uint32* __restrict__ h2,   // gather source (layer-2 output)
               const uint32* __restrict__ h0,
               const uint32* __restrict__ h1,
               float* __restrict__ out,
               const int* __restrict__ cols,
               const float* __restrict__ vals,
               const int* __restrict__ rowptr,
               int n_nodes) {
    int wave = (int)((blockIdx.x * blockDim.x + threadIdx.x) >> 6);
    int lane = threadIdx.x & 63;
    if (wave >= n_nodes) return;

    int lo = __builtin_amdgcn_readfirstlane(rowptr[wave]);
    int hi = __builtin_amdgcn_readfirstlane(rowptr[wave + 1]);

    float sx = 0.f, sy = 0.f;                  // h3 row (fp32)
    row_dispatch(h2, cols, vals, lo, hi, lane, sx, sy);

    uint32 off = (uint32)wave * 64u + (uint32)lane;
    // read-once linear streams: nontemporal so they don't evict gather-hot h2
    uint32 u0 = __builtin_nontemporal_load(h0 + off);
    uint32 u1 = __builtin_nontemporal_load(h1 + off);
    uint32 u2 = h2[off];

    float ax = __uint_as_float(u0 << 16) + __uint_as_float(u1 << 16)
             + __uint_as_float(u2 << 16) + sx;
    float ay = __uint_as_float(u0 & 0xFFFF0000u) + __uint_as_float(u1 & 0xFFFF0000u)
             + __uint_as_float(u2 & 0xFFFF0000u) + sy;

    // pack two fp32 into u64 so the nontemporal builtin accepts the pointer
    u64 pair = (u64)__float_as_uint(ax * 0.25f)
             | ((u64)__float_as_uint(ay * 0.25f) << 32);
    u64* outp = reinterpret_cast<u64*>(out + (size_t)off * 2);
    __builtin_nontemporal_store(pair, outp);
}

extern "C" void kernel_launch(void* const* d_in, const int* in_sizes, int n_in,
                              void* d_out, int out_size, void* d_ws, size_t ws_size,
                              hipStream_t stream) {
    const float* ue   = (const float*)d_in[0];
    const float* ie   = (const float*)d_in[1];
    const int*   rows = (const int*)  d_in[2];
    const int*   cols = (const int*)  d_in[3];
    const float* vals = (const float*)d_in[4];
    float* out = (float*)d_out;

    char* ws = (char*)d_ws;
    int* rowptr = (int*)ws;
    size_t off = (((size_t)(NNODES + 1) * sizeof(int)) + 255) & ~(size_t)255;
    size_t hbytes = (size_t)NNODES * 64 * sizeof(uint32);
    uint32* h0 = (uint32*)(ws + off);
    uint32* h1 = (uint32*)(ws + off + hbytes);
    uint32* h2 = (uint32*)(ws + off + 2 * hbytes);

    // 1. row_ptr
    build_rowptr<<<(NNODES + 1 + 255) / 256, 256, 0, stream>>>(
        rows, rowptr, NNODES, NEDGES);

    // 2. init h0 (bf16)
    {
        int n_user4  = NUSERS * DIM / 4;
        int n_total4 = NNODES * DIM / 4;
        init_kernel<<<(n_total4 + 255) / 256, 256, 0, stream>>>(
            (const float4*)ue, (const float4*)ie, (uint2*)h0,
            n_user4, n_total4);
    }

    // 3. layers
    int waves_per_block = 256 / 64;
    int blocks = (NNODES + waves_per_block - 1) / waves_per_block;

    spmm_mid <<<blocks, 256, 0, stream>>>(h0, h1, cols, vals, rowptr, NNODES);
    spmm_mid <<<blocks, 256, 0, stream>>>(h1, h2, cols, vals, rowptr, NNODES);
    spmm_last<<<blocks, 256, 0, stream>>>(h2, h0, h1, out, cols, vals, rowptr, NNODES);
}